// Round 1
// baseline (1047.100 us; speedup 1.0000x reference)
//
#include <hip/hip_runtime.h>

#define F 128
#define H 64
#define O 16

// ---------- CSR build ----------
__global__ void k_zero(int* __restrict__ p, int n) {
    int i = blockIdx.x * blockDim.x + threadIdx.x;
    if (i < n) p[i] = 0;
}

__global__ void k_degree(const int* __restrict__ dstv, int* __restrict__ deg, int E) {
    int i = blockIdx.x * blockDim.x + threadIdx.x;
    if (i < E) atomicAdd(&deg[dstv[i]], 1);
}

__global__ void k_dis(const int* __restrict__ deg, float* __restrict__ dis, int N) {
    int i = blockIdx.x * blockDim.x + threadIdx.x;
    if (i < N) dis[i] = rsqrtf((float)deg[i] + 1.0f);
}

// block-level exclusive scan of deg -> local (stored in row_ptr), block sums -> partials
__global__ void k_scan1(const int* __restrict__ deg, int* __restrict__ local,
                        int* __restrict__ partials, int N) {
    __shared__ int s[256];
    int tid = threadIdx.x;
    int i = blockIdx.x * 256 + tid;
    int v = (i < N) ? deg[i] : 0;
    s[tid] = v;
    __syncthreads();
    for (int off = 1; off < 256; off <<= 1) {
        int t = (tid >= off) ? s[tid - off] : 0;
        __syncthreads();
        s[tid] += t;
        __syncthreads();
    }
    if (i < N) local[i] = s[tid] - v;  // exclusive within block
    if (tid == 255) partials[blockIdx.x] = s[255];
}

// single block scans the (<=1024) block sums in-place to exclusive
__global__ void k_scan2(int* __restrict__ partials, int NB) {
    __shared__ int s[1024];
    int tid = threadIdx.x;
    int v = (tid < NB) ? partials[tid] : 0;
    s[tid] = v;
    __syncthreads();
    for (int off = 1; off < 1024; off <<= 1) {
        int t = (tid >= off) ? s[tid - off] : 0;
        __syncthreads();
        s[tid] += t;
        __syncthreads();
    }
    partials[tid] = s[tid] - v;  // exclusive
}

// add block offsets, produce row_ptr (N+1) and init cursor
__global__ void k_scan3(int* __restrict__ row_ptr, int* __restrict__ cursor,
                        const int* __restrict__ partials, int N, int E) {
    int i = blockIdx.x * blockDim.x + threadIdx.x;
    if (i < N) {
        int v = row_ptr[i] + partials[i >> 8];
        row_ptr[i] = v;
        cursor[i] = v;
    } else if (i == N) {
        row_ptr[N] = E;
    }
}

__global__ void k_scatter(const int* __restrict__ src, const int* __restrict__ dstv,
                          int* __restrict__ cursor, int* __restrict__ col, int E) {
    int i = blockIdx.x * blockDim.x + threadIdx.x;
    if (i < E) {
        int d = dstv[i];
        int pos = atomicAdd(&cursor[d], 1);
        col[pos] = src[i];
    }
}

// ---------- layer 1: h1 = x @ W1 ----------
__global__ __launch_bounds__(256) void k_gemm1(const float* __restrict__ x,
                                               const float* __restrict__ W1,
                                               float* __restrict__ h1, int N) {
    __shared__ float w[F * H];  // 32 KB
    for (int t = threadIdx.x; t < F * H; t += 256) w[t] = W1[t];
    __syncthreads();
    int wave = threadIdx.x >> 6, lane = threadIdx.x & 63;
    for (int r = blockIdx.x * 4 + wave; r < N; r += gridDim.x * 4) {
        const float* xr = x + (size_t)r * F;
        float acc = 0.f;
#pragma unroll
        for (int k = 0; k < F; k++) acc = fmaf(xr[k], w[k * H + lane], acc);
        h1[(size_t)r * H + lane] = acc;
    }
}

// ---------- layer 1 aggregation: one wave per node, lane = feature ----------
__global__ __launch_bounds__(256) void k_gather1(const float* __restrict__ h1,
                                                 const float* __restrict__ dis,
                                                 const int* __restrict__ row_ptr,
                                                 const int* __restrict__ col,
                                                 const float* __restrict__ b1,
                                                 float* __restrict__ z, int N) {
    int node = blockIdx.x * 4 + (threadIdx.x >> 6);
    if (node >= N) return;
    int lane = threadIdx.x & 63;
    float dn = dis[node];
    float acc = h1[(size_t)node * H + lane] * dn * dn;  // self loop
    int p = row_ptr[node], e = row_ptr[node + 1];
    for (; p < e; p++) {
        int s = col[p];
        acc = fmaf(h1[(size_t)s * H + lane], dis[s] * dn, acc);
    }
    acc += b1[lane];
    z[(size_t)node * H + lane] = fmaxf(acc, 0.f);  // relu
}

// ---------- layer 2: h2 = z @ W2 ----------
__global__ __launch_bounds__(256) void k_gemm2(const float* __restrict__ z,
                                               const float* __restrict__ W2,
                                               float* __restrict__ h2, int N) {
    __shared__ float w[H * O];  // 4 KB
    for (int t = threadIdx.x; t < H * O; t += 256) w[t] = W2[t];
    __syncthreads();
    int idx = blockIdx.x * 256 + threadIdx.x;
    int row = idx >> 4, j = idx & 15;
    if (row >= N) return;
    const float* zr = z + (size_t)row * H;
    float acc = 0.f;
#pragma unroll
    for (int k = 0; k < H; k++) acc = fmaf(zr[k], w[k * O + j], acc);
    h2[idx] = acc;
}

// ---------- layer 2 aggregation: 16 lanes per node ----------
__global__ __launch_bounds__(256) void k_gather2(const float* __restrict__ h2,
                                                 const float* __restrict__ dis,
                                                 const int* __restrict__ row_ptr,
                                                 const int* __restrict__ col,
                                                 const float* __restrict__ b2,
                                                 float* __restrict__ z2, int N) {
    int idx = blockIdx.x * 256 + threadIdx.x;
    int node = idx >> 4, j = idx & 15;
    if (node >= N) return;
    float dn = dis[node];
    float acc = h2[idx] * dn * dn;  // self loop
    int p = row_ptr[node], e = row_ptr[node + 1];
    for (; p < e; p++) {
        int s = col[p];
        acc = fmaf(h2[(size_t)s * O + j], dis[s] * dn, acc);
    }
    z2[idx] = acc + b2[j];
}

// ---------- link prediction logits ----------
__global__ __launch_bounds__(256) void k_logits(const float* __restrict__ z2,
                                                const int* __restrict__ pos,
                                                const int* __restrict__ neg,
                                                float* __restrict__ out, int P, int Q) {
    int i = blockIdx.x * 256 + threadIdx.x;
    if (i >= P + Q) return;
    int a, b;
    if (i < P) { a = pos[i]; b = pos[P + i]; }
    else       { int t = i - P; a = neg[t]; b = neg[Q + t]; }
    const float4* A = (const float4*)(z2 + (size_t)a * O);
    const float4* B = (const float4*)(z2 + (size_t)b * O);
    float acc = 0.f;
#pragma unroll
    for (int k = 0; k < 4; k++) {
        float4 va = A[k], vb = B[k];
        acc += va.x * vb.x + va.y * vb.y + va.z * vb.z + va.w * vb.w;
    }
    out[i] = acc;
}

extern "C" void kernel_launch(void* const* d_in, const int* in_sizes, int n_in,
                              void* d_out, int out_size, void* d_ws, size_t ws_size,
                              hipStream_t stream) {
    const float* x  = (const float*)d_in[0];
    const int*   ei = (const int*)d_in[1];
    const int*   pos = (const int*)d_in[2];
    const int*   neg = (const int*)d_in[3];
    const float* W1 = (const float*)d_in[4];
    const float* b1 = (const float*)d_in[5];
    const float* W2 = (const float*)d_in[6];
    const float* b2 = (const float*)d_in[7];
    float* out = (float*)d_out;

    int N = in_sizes[0] / F;
    int E = in_sizes[1] / 2;
    int P = in_sizes[2] / 2;
    int Q = in_sizes[3] / 2;
    const int* src  = ei;
    const int* dstv = ei + E;

    int NB = (N + 255) / 256;      // blocks for scan, <= 1024
    int Npad = NB * 256;
    int Epad = (E + 63) & ~63;

    // workspace layout (all offsets 256B-aligned given 256-mult counts)
    int*   deg      = (int*)d_ws;
    float* dis      = (float*)(deg + Npad);
    int*   row_ptr  = (int*)(dis + Npad);       // N+1 entries (Npad+256 reserved)
    int*   cursor   = row_ptr + Npad + 256;
    int*   partials = cursor + Npad;            // 1024 entries
    int*   col      = partials + 1024;          // E entries
    float* h1       = (float*)(col + Epad);     // N*H
    float* z        = h1 + (size_t)N * H;       // N*H
    float* h2       = z + (size_t)N * H;        // N*O
    float* z2       = h2 + (size_t)N * O;       // N*O

    // CSR build
    k_zero<<<(Npad + 255) / 256, 256, 0, stream>>>(deg, Npad);
    k_degree<<<(E + 255) / 256, 256, 0, stream>>>(dstv, deg, E);
    k_dis<<<(N + 255) / 256, 256, 0, stream>>>(deg, dis, N);
    k_scan1<<<NB, 256, 0, stream>>>(deg, row_ptr, partials, N);
    k_scan2<<<1, 1024, 0, stream>>>(partials, NB);
    k_scan3<<<(N + 256) / 256, 256, 0, stream>>>(row_ptr, cursor, partials, N, E);
    k_scatter<<<(E + 255) / 256, 256, 0, stream>>>(src, dstv, cursor, col, E);

    // layer 1
    k_gemm1<<<1024, 256, 0, stream>>>(x, W1, h1, N);
    k_gather1<<<(N + 3) / 4, 256, 0, stream>>>(h1, dis, row_ptr, col, b1, z, N);

    // layer 2
    k_gemm2<<<(N * O + 255) / 256, 256, 0, stream>>>(z, W2, h2, N);
    k_gather2<<<(N * O + 255) / 256, 256, 0, stream>>>(h2, dis, row_ptr, col, b2, z2, N);

    // logits
    k_logits<<<(P + Q + 255) / 256, 256, 0, stream>>>(z2, pos, neg, out, P, Q);
}

// Round 2
// 813.653 us; speedup vs baseline: 1.2869x; 1.2869x over previous
//
#include <hip/hip_runtime.h>

#define F 128
#define H 64
#define O 16

// ---------- CSR build ----------
__global__ void k_zero(int* __restrict__ p, int n) {
    int i = blockIdx.x * blockDim.x + threadIdx.x;
    if (i < n) p[i] = 0;
}

__global__ void k_degree(const int* __restrict__ dstv, int* __restrict__ deg, int E) {
    int i = blockIdx.x * blockDim.x + threadIdx.x;
    if (i < E) atomicAdd(&deg[dstv[i]], 1);
}

__global__ void k_dis(const int* __restrict__ deg, float* __restrict__ dis, int N) {
    int i = blockIdx.x * blockDim.x + threadIdx.x;
    if (i < N) dis[i] = rsqrtf((float)deg[i] + 1.0f);
}

// block-level exclusive scan of deg -> local (stored in row_ptr), block sums -> partials
__global__ void k_scan1(const int* __restrict__ deg, int* __restrict__ local,
                        int* __restrict__ partials, int N) {
    __shared__ int s[256];
    int tid = threadIdx.x;
    int i = blockIdx.x * 256 + tid;
    int v = (i < N) ? deg[i] : 0;
    s[tid] = v;
    __syncthreads();
    for (int off = 1; off < 256; off <<= 1) {
        int t = (tid >= off) ? s[tid - off] : 0;
        __syncthreads();
        s[tid] += t;
        __syncthreads();
    }
    if (i < N) local[i] = s[tid] - v;  // exclusive within block
    if (tid == 255) partials[blockIdx.x] = s[255];
}

__global__ void k_scan2(int* __restrict__ partials, int NB) {
    __shared__ int s[1024];
    int tid = threadIdx.x;
    int v = (tid < NB) ? partials[tid] : 0;
    s[tid] = v;
    __syncthreads();
    for (int off = 1; off < 1024; off <<= 1) {
        int t = (tid >= off) ? s[tid - off] : 0;
        __syncthreads();
        s[tid] += t;
        __syncthreads();
    }
    partials[tid] = s[tid] - v;  // exclusive
}

__global__ void k_scan3(int* __restrict__ row_ptr, int* __restrict__ cursor,
                        const int* __restrict__ partials, int N, int E) {
    int i = blockIdx.x * blockDim.x + threadIdx.x;
    if (i < N) {
        int v = row_ptr[i] + partials[i >> 8];
        row_ptr[i] = v;
        cursor[i] = v;
    } else if (i == N) {
        row_ptr[N] = E;
    }
}

__global__ void k_scatter(const int* __restrict__ src, const int* __restrict__ dstv,
                          int* __restrict__ cursor, int* __restrict__ col, int E) {
    int i = blockIdx.x * blockDim.x + threadIdx.x;
    if (i < E) {
        int d = dstv[i];
        int pos = atomicAdd(&cursor[d], 1);
        col[pos] = src[i];
    }
}

// ---------- layer 1: h1p = (x @ W1) * dis[row] ----------
__global__ __launch_bounds__(256) void k_gemm1(const float* __restrict__ x,
                                               const float* __restrict__ W1,
                                               const float* __restrict__ dis,
                                               float* __restrict__ h1p, int N) {
    __shared__ float w[F * H];  // 32 KB
    for (int t = threadIdx.x; t < F * H; t += 256) w[t] = W1[t];
    __syncthreads();
    int wave = threadIdx.x >> 6, lane = threadIdx.x & 63;
    for (int r = blockIdx.x * 4 + wave; r < N; r += gridDim.x * 4) {
        const float* xr = x + (size_t)r * F;
        float acc = 0.f;
#pragma unroll
        for (int k = 0; k < F; k++) acc = fmaf(xr[k], w[k * H + lane], acc);
        h1p[(size_t)r * H + lane] = acc * dis[r];
    }
}

// ---------- layer 1 aggregation: 1 wave/node, 4 edges in flight ----------
// z[i] = relu( dis[i]*( sum_{s in N(i)} h1p[s] + h1p[i] ) + b1 )
__global__ __launch_bounds__(256) void k_gather1(const float* __restrict__ h1p,
                                                 const float* __restrict__ dis,
                                                 const int* __restrict__ row_ptr,
                                                 const int* __restrict__ col,
                                                 const float* __restrict__ b1,
                                                 float* __restrict__ z, int N) {
    int node = blockIdx.x * 4 + (threadIdx.x >> 6);
    if (node >= N) return;
    int lane = threadIdx.x & 63;
    int g = lane >> 4;    // edge group 0..3
    int t = lane & 15;    // feature quad: features t*4 .. t*4+3
    float4 acc = {0.f, 0.f, 0.f, 0.f};
    int e = row_ptr[node + 1];
#pragma unroll 4
    for (int p = row_ptr[node] + g; p < e; p += 4) {
        int s = col[p];
        float4 v = *(const float4*)(h1p + (size_t)s * H + t * 4);
        acc.x += v.x; acc.y += v.y; acc.z += v.z; acc.w += v.w;
    }
#pragma unroll
    for (int off = 16; off < 64; off <<= 1) {
        acc.x += __shfl_xor(acc.x, off);
        acc.y += __shfl_xor(acc.y, off);
        acc.z += __shfl_xor(acc.z, off);
        acc.w += __shfl_xor(acc.w, off);
    }
    if (g == 0) {
        float dn = dis[node];
        float4 self = *(const float4*)(h1p + (size_t)node * H + t * 4);
        float4 bb = *(const float4*)(b1 + t * 4);
        float4 o;
        o.x = fmaxf(fmaf(acc.x + self.x, dn, bb.x), 0.f);
        o.y = fmaxf(fmaf(acc.y + self.y, dn, bb.y), 0.f);
        o.z = fmaxf(fmaf(acc.z + self.z, dn, bb.z), 0.f);
        o.w = fmaxf(fmaf(acc.w + self.w, dn, bb.w), 0.f);
        *(float4*)(z + (size_t)node * H + t * 4) = o;
    }
}

// ---------- layer 2: h2p = (z @ W2) * dis[row] ----------
__global__ __launch_bounds__(256) void k_gemm2(const float* __restrict__ z,
                                               const float* __restrict__ W2,
                                               const float* __restrict__ dis,
                                               float* __restrict__ h2p, int N) {
    __shared__ float w[H * O];  // 4 KB
    for (int t = threadIdx.x; t < H * O; t += 256) w[t] = W2[t];
    __syncthreads();
    int idx = blockIdx.x * 256 + threadIdx.x;
    int row = idx >> 4, j = idx & 15;
    if (row >= N) return;
    const float* zr = z + (size_t)row * H;
    float acc = 0.f;
#pragma unroll
    for (int k = 0; k < H; k++) acc = fmaf(zr[k], w[k * O + j], acc);
    h2p[idx] = acc * dis[row];
}

// ---------- layer 2 aggregation: 1 wave/node, 16 edges in flight ----------
// z2[i] = dis[i]*( sum_{s in N(i)} h2p[s] + h2p[i] ) + b2
__global__ __launch_bounds__(256) void k_gather2(const float* __restrict__ h2p,
                                                 const float* __restrict__ dis,
                                                 const int* __restrict__ row_ptr,
                                                 const int* __restrict__ col,
                                                 const float* __restrict__ b2,
                                                 float* __restrict__ z2, int N) {
    int node = blockIdx.x * 4 + (threadIdx.x >> 6);
    if (node >= N) return;
    int lane = threadIdx.x & 63;
    int g = lane >> 2;    // edge group 0..15
    int t = lane & 3;     // feature quad: features t*4 .. t*4+3
    float4 acc = {0.f, 0.f, 0.f, 0.f};
    int e = row_ptr[node + 1];
    for (int p = row_ptr[node] + g; p < e; p += 16) {
        int s = col[p];
        float4 v = *(const float4*)(h2p + (size_t)s * O + t * 4);
        acc.x += v.x; acc.y += v.y; acc.z += v.z; acc.w += v.w;
    }
#pragma unroll
    for (int off = 4; off < 64; off <<= 1) {
        acc.x += __shfl_xor(acc.x, off);
        acc.y += __shfl_xor(acc.y, off);
        acc.z += __shfl_xor(acc.z, off);
        acc.w += __shfl_xor(acc.w, off);
    }
    if (g == 0) {
        float dn = dis[node];
        float4 self = *(const float4*)(h2p + (size_t)node * O + t * 4);
        float4 bb = *(const float4*)(b2 + t * 4);
        float4 o;
        o.x = fmaf(acc.x + self.x, dn, bb.x);
        o.y = fmaf(acc.y + self.y, dn, bb.y);
        o.z = fmaf(acc.z + self.z, dn, bb.z);
        o.w = fmaf(acc.w + self.w, dn, bb.w);
        *(float4*)(z2 + (size_t)node * O + t * 4) = o;
    }
}

// ---------- link prediction logits: 4 lanes per pair ----------
__global__ __launch_bounds__(256) void k_logits(const float* __restrict__ z2,
                                                const int* __restrict__ pos,
                                                const int* __restrict__ neg,
                                                float* __restrict__ out, int P, int Q) {
    int tid = blockIdx.x * 256 + threadIdx.x;
    int i = tid >> 2;
    if (i >= P + Q) return;
    int k = tid & 3;
    int a, b;
    if (i < P) { a = pos[i]; b = pos[P + i]; }
    else       { int t = i - P; a = neg[t]; b = neg[Q + t]; }
    float4 va = *(const float4*)(z2 + (size_t)a * O + k * 4);
    float4 vb = *(const float4*)(z2 + (size_t)b * O + k * 4);
    float r = va.x * vb.x + va.y * vb.y + va.z * vb.z + va.w * vb.w;
    r += __shfl_xor(r, 1);
    r += __shfl_xor(r, 2);
    if (k == 0) out[i] = r;
}

extern "C" void kernel_launch(void* const* d_in, const int* in_sizes, int n_in,
                              void* d_out, int out_size, void* d_ws, size_t ws_size,
                              hipStream_t stream) {
    const float* x   = (const float*)d_in[0];
    const int*   ei  = (const int*)d_in[1];
    const int*   pos = (const int*)d_in[2];
    const int*   neg = (const int*)d_in[3];
    const float* W1  = (const float*)d_in[4];
    const float* b1  = (const float*)d_in[5];
    const float* W2  = (const float*)d_in[6];
    const float* b2  = (const float*)d_in[7];
    float* out = (float*)d_out;

    int N = in_sizes[0] / F;
    int E = in_sizes[1] / 2;
    int P = in_sizes[2] / 2;
    int Q = in_sizes[3] / 2;
    const int* src  = ei;
    const int* dstv = ei + E;

    int NB = (N + 255) / 256;      // blocks for scan, <= 1024
    int Npad = NB * 256;
    int Epad = (E + 63) & ~63;

    // workspace layout (all offsets 256B-aligned)
    int*   deg      = (int*)d_ws;
    float* dis      = (float*)(deg + Npad);
    int*   row_ptr  = (int*)(dis + Npad);       // N+1 entries (Npad+256 reserved)
    int*   cursor   = row_ptr + Npad + 256;
    int*   partials = cursor + Npad;            // 1024 entries
    int*   col      = partials + 1024;          // E entries
    float* h1p      = (float*)(col + Epad);     // N*H
    float* z        = h1p + (size_t)N * H;      // N*H
    float* h2p      = z + (size_t)N * H;        // N*O
    float* z2       = h2p + (size_t)N * O;      // N*O

    // CSR build
    k_zero<<<(Npad + 255) / 256, 256, 0, stream>>>(deg, Npad);
    k_degree<<<(E + 255) / 256, 256, 0, stream>>>(dstv, deg, E);
    k_dis<<<(N + 255) / 256, 256, 0, stream>>>(deg, dis, N);
    k_scan1<<<NB, 256, 0, stream>>>(deg, row_ptr, partials, N);
    k_scan2<<<1, 1024, 0, stream>>>(partials, NB);
    k_scan3<<<(N + 256) / 256, 256, 0, stream>>>(row_ptr, cursor, partials, N, E);
    k_scatter<<<(E + 255) / 256, 256, 0, stream>>>(src, dstv, cursor, col, E);

    // layer 1
    k_gemm1<<<1024, 256, 0, stream>>>(x, W1, dis, h1p, N);
    k_gather1<<<(N + 3) / 4, 256, 0, stream>>>(h1p, dis, row_ptr, col, b1, z, N);

    // layer 2
    k_gemm2<<<(N * O + 255) / 256, 256, 0, stream>>>(z, W2, dis, h2p, N);
    k_gather2<<<(N + 3) / 4, 256, 0, stream>>>(h2p, dis, row_ptr, col, b2, z2, N);

    // logits
    k_logits<<<((P + Q) * 4 + 255) / 256, 256, 0, stream>>>(z2, pos, neg, out, P, Q);
}